// Round 1
// baseline (2145.907 us; speedup 1.0000x reference)
//
#include <hip/hip_runtime.h>
#include <hip/hip_bf16.h>

#define B_ 4
#define H_ 8
#define N_ 2048
#define D_ 512
#define DH 64
#define TQ 32
#define TK 32
#define MAXREL 199   // MAX_REL-1

// ---------------- LayerNorm: one block per row of 512 ----------------
__global__ __launch_bounds__(256) void ln_kernel(const float* __restrict__ x,
                                                 const float* __restrict__ gamma,
                                                 const float* __restrict__ beta,
                                                 float* __restrict__ xn) {
    __shared__ float sbuf[4];
    const int row = blockIdx.x;
    const int t = threadIdx.x;
    const float* xr = x + (size_t)row * D_;

    float v0 = xr[t];
    float v1 = xr[t + 256];

    // pass 1: mean
    float s = v0 + v1;
    for (int o = 32; o > 0; o >>= 1) s += __shfl_down(s, o);
    if ((t & 63) == 0) sbuf[t >> 6] = s;
    __syncthreads();
    float mu = (sbuf[0] + sbuf[1] + sbuf[2] + sbuf[3]) * (1.0f / D_);
    __syncthreads();

    // pass 2: var
    float d0 = v0 - mu, d1 = v1 - mu;
    float s2 = d0 * d0 + d1 * d1;
    for (int o = 32; o > 0; o >>= 1) s2 += __shfl_down(s2, o);
    if ((t & 63) == 0) sbuf[t >> 6] = s2;
    __syncthreads();
    float var = (sbuf[0] + sbuf[1] + sbuf[2] + sbuf[3]) * (1.0f / D_);
    float rs = rsqrtf(var + 1e-5f);

    float* yr = xn + (size_t)row * D_;
    yr[t]       = d0 * rs * gamma[t]       + beta[t];
    yr[t + 256] = d1 * rs * gamma[t + 256] + beta[t + 256];
}

// ---------------- generic fp32 GEMM: C[M,N] = A[M,K]*B[K,N] (+bias) ----------------
// 64x64 tile, KT=16, 256 threads (16x16), 4x4 per thread. M,N %64==0, K %16==0.
__global__ __launch_bounds__(256) void gemm_bias_kernel(const float* __restrict__ A,
                                                        const float* __restrict__ Bm,
                                                        const float* __restrict__ bias,
                                                        float* __restrict__ C,
                                                        int M, int N, int K) {
    __shared__ float As[64][17];
    __shared__ float Bs[16][65];
    const int c0 = blockIdx.x * 64;
    const int r0 = blockIdx.y * 64;
    const int t = threadIdx.x;
    const int tx = t & 15, ty = t >> 4;

    float acc[4][4] = {};

    for (int k0 = 0; k0 < K; k0 += 16) {
        #pragma unroll
        for (int i = 0; i < 4; i++) {
            int idx = t + i * 256;
            int r = idx >> 4, kk = idx & 15;
            As[r][kk] = A[(size_t)(r0 + r) * K + k0 + kk];
        }
        #pragma unroll
        for (int i = 0; i < 4; i++) {
            int idx = t + i * 256;
            int kk = idx >> 6, c = idx & 63;
            Bs[kk][c] = Bm[(size_t)(k0 + kk) * N + c0 + c];
        }
        __syncthreads();
        #pragma unroll
        for (int kk = 0; kk < 16; kk++) {
            float a[4], b[4];
            #pragma unroll
            for (int i = 0; i < 4; i++) a[i] = As[ty * 4 + i][kk];
            #pragma unroll
            for (int j = 0; j < 4; j++) b[j] = Bs[kk][tx * 4 + j];
            #pragma unroll
            for (int i = 0; i < 4; i++)
                #pragma unroll
                for (int j = 0; j < 4; j++) acc[i][j] += a[i] * b[j];
        }
        __syncthreads();
    }

    #pragma unroll
    for (int i = 0; i < 4; i++) {
        int r = r0 + ty * 4 + i;
        #pragma unroll
        for (int j = 0; j < 4; j++) {
            int c = c0 + tx * 4 + j;
            float bv = bias ? bias[c] : 0.0f;
            C[(size_t)r * N + c] = acc[i][j] + bv;
        }
    }
}

// ---------------- fused attention (flash-style, online softmax) ----------------
// qkv layout: [B, N, 1536] rows; q at col h*64+dd, k at 512+h*64+dd, v at 1024+...
// out layout: [B, N, 512] with head h occupying cols h*64..h*64+63
__global__ __launch_bounds__(256) void attn_kernel(const float* __restrict__ qkv,
                                                   const float* __restrict__ rel_table,
                                                   const int* __restrict__ mask,
                                                   float* __restrict__ out) {
    __shared__ float q_s[TQ][DH + 1];
    __shared__ float k_s[TK][DH + 1];
    __shared__ float v_s[TK][DH + 1];
    __shared__ float s_s[TQ][TK + 1];
    __shared__ float row_m[TQ], row_l[TQ], row_a[TQ];

    const int qt = blockIdx.x;
    const int h  = blockIdx.y;
    const int b  = blockIdx.z;
    const int n0 = qt * TQ;
    const int t = threadIdx.x;
    const int dd = t & 63;
    const int rg = t >> 6;              // 4 row groups of 8 rows each
    const size_t base = (size_t)b * N_ * 1536 + h * 64;

    // load Q tile
    #pragma unroll
    for (int i = 0; i < 8; i++) {
        int idx = t + i * 256;
        int r = idx >> 6, d2 = idx & 63;
        q_s[r][d2] = qkv[base + (size_t)(n0 + r) * 1536 + d2];
    }
    if (t < TQ) { row_m[t] = -1e30f; row_l[t] = 0.0f; }

    float acc[8];
    #pragma unroll
    for (int i = 0; i < 8; i++) acc[i] = 0.0f;
    __syncthreads();

    for (int j0 = 0; j0 < N_; j0 += TK) {
        // load K/V tiles
        #pragma unroll
        for (int i = 0; i < 8; i++) {
            int idx = t + i * 256;
            int r = idx >> 6, d2 = idx & 63;
            size_t ro = base + (size_t)(j0 + r) * 1536 + d2;
            k_s[r][d2] = qkv[ro + 512];
            v_s[r][d2] = qkv[ro + 1024];
        }
        __syncthreads();

        // scores: 4 entries per thread
        #pragma unroll
        for (int e = 0; e < 4; e++) {
            int idx = t + e * 256;
            int r = idx >> 5, c = idx & 31;
            float s = 0.0f;
            #pragma unroll
            for (int d2 = 0; d2 < 64; d2++) s += q_s[r][d2] * k_s[c][d2];
            int n = n0 + r, m = j0 + c;
            int relidx = n - m;
            relidx = relidx < -MAXREL ? -MAXREL : (relidx > MAXREL ? MAXREL : relidx);
            s = s * 0.125f + rel_table[relidx + MAXREL];
            if (mask[n * N_ + m] == 0) s = -1e9f;
            s_s[r][c] = s;
        }
        __syncthreads();

        // online softmax stats (one thread per row)
        if (t < TQ) {
            float mo = row_m[t], mx = mo;
            #pragma unroll
            for (int c = 0; c < TK; c++) mx = fmaxf(mx, s_s[t][c]);
            float a = __expf(mo - mx);
            float sum = 0.0f;
            #pragma unroll
            for (int c = 0; c < TK; c++) {
                float p = __expf(s_s[t][c] - mx);
                s_s[t][c] = p;
                sum += p;
            }
            row_m[t] = mx;
            row_l[t] = row_l[t] * a + sum;
            row_a[t] = a;
        }
        __syncthreads();

        // acc update: thread owns (rows rg*8..rg*8+7, col dd)
        #pragma unroll
        for (int i = 0; i < 8; i++) {
            int r = rg * 8 + i;
            float o = acc[i] * row_a[r];
            #pragma unroll
            for (int c = 0; c < TK; c++) o += s_s[r][c] * v_s[c][dd];
            acc[i] = o;
        }
        __syncthreads();
    }

    // epilogue
    #pragma unroll
    for (int i = 0; i < 8; i++) {
        int r = rg * 8 + i;
        int n = n0 + r;
        out[((size_t)b * N_ + n) * 512 + h * 64 + dd] = acc[i] / row_l[r];
    }
}

extern "C" void kernel_launch(void* const* d_in, const int* in_sizes, int n_in,
                              void* d_out, int out_size, void* d_ws, size_t ws_size,
                              hipStream_t stream) {
    const float* x     = (const float*)d_in[0];
    const float* gamma = (const float*)d_in[1];
    const float* beta  = (const float*)d_in[2];
    const float* Wqkv  = (const float*)d_in[3];
    const float* Wout  = (const float*)d_in[4];
    const float* bout  = (const float*)d_in[5];
    const float* rel   = (const float*)d_in[6];
    const int*   mask  = (const int*)d_in[7];
    float* out = (float*)d_out;

    float* ws   = (float*)d_ws;
    float* xn   = ws;                    // 8192*512   = 4,194,304 floats
    float* qkv  = ws + 4194304;          // 8192*1536  = 12,582,912 floats
    float* attn = ws + 16777216;         // 8192*512   = 4,194,304 floats

    // 1. LayerNorm
    ln_kernel<<<B_ * N_, 256, 0, stream>>>(x, gamma, beta, xn);

    // 2. QKV projection: [8192,512] x [512,1536]
    gemm_bias_kernel<<<dim3(1536 / 64, 8192 / 64), 256, 0, stream>>>(
        xn, Wqkv, nullptr, qkv, B_ * N_, 1536, D_);

    // 3. fused attention
    attn_kernel<<<dim3(N_ / TQ, H_, B_), 256, 0, stream>>>(qkv, rel, mask, attn);

    // 4. output projection + bias: [8192,512] x [512,512]
    gemm_bias_kernel<<<dim3(512 / 64, 8192 / 64), 256, 0, stream>>>(
        attn, Wout, bout, out, B_ * N_, 512, D_);
}

// Round 2
// 798.694 us; speedup vs baseline: 2.6868x; 2.6868x over previous
//
#include <hip/hip_runtime.h>

typedef __attribute__((ext_vector_type(8))) short bf16x8;
typedef __attribute__((ext_vector_type(4))) float f32x4;
typedef unsigned short ushort_t;

#define B_ 4
#define H_ 8
#define N_ 2048
#define D_ 512
#define MAXREL 199   // MAX_REL-1

__device__ __forceinline__ ushort_t f2bf(float f) {
    union { float f; unsigned u; } v; v.f = f;
    unsigned r = v.u + 0x7fffu + ((v.u >> 16) & 1u);
    return (ushort_t)(r >> 16);
}

// ---------------- LayerNorm: one block per row of 512 ----------------
__global__ __launch_bounds__(256) void ln_kernel(const float* __restrict__ x,
                                                 const float* __restrict__ gamma,
                                                 const float* __restrict__ beta,
                                                 float* __restrict__ xn) {
    __shared__ float sbuf[4];
    const int row = blockIdx.x;
    const int t = threadIdx.x;
    const float* xr = x + (size_t)row * D_;

    float v0 = xr[t];
    float v1 = xr[t + 256];

    float s = v0 + v1;
    for (int o = 32; o > 0; o >>= 1) s += __shfl_down(s, o);
    if ((t & 63) == 0) sbuf[t >> 6] = s;
    __syncthreads();
    float mu = (sbuf[0] + sbuf[1] + sbuf[2] + sbuf[3]) * (1.0f / D_);
    __syncthreads();

    float d0 = v0 - mu, d1 = v1 - mu;
    float s2 = d0 * d0 + d1 * d1;
    for (int o = 32; o > 0; o >>= 1) s2 += __shfl_down(s2, o);
    if ((t & 63) == 0) sbuf[t >> 6] = s2;
    __syncthreads();
    float var = (sbuf[0] + sbuf[1] + sbuf[2] + sbuf[3]) * (1.0f / D_);
    float rs = rsqrtf(var + 1e-5f);

    float* yr = xn + (size_t)row * D_;
    yr[t]       = d0 * rs * gamma[t]       + beta[t];
    yr[t + 256] = d1 * rs * gamma[t + 256] + beta[t + 256];
}

// ---------------- fp32 GEMM for the output projection ----------------
__global__ __launch_bounds__(256) void gemm_bias_kernel(const float* __restrict__ A,
                                                        const float* __restrict__ Bm,
                                                        const float* __restrict__ bias,
                                                        float* __restrict__ C,
                                                        int M, int N, int K) {
    __shared__ float As[64][17];
    __shared__ float Bs[16][65];
    const int c0 = blockIdx.x * 64;
    const int r0 = blockIdx.y * 64;
    const int t = threadIdx.x;
    const int tx = t & 15, ty = t >> 4;

    float acc[4][4] = {};

    for (int k0 = 0; k0 < K; k0 += 16) {
        #pragma unroll
        for (int i = 0; i < 4; i++) {
            int idx = t + i * 256;
            int r = idx >> 4, kk = idx & 15;
            As[r][kk] = A[(size_t)(r0 + r) * K + k0 + kk];
        }
        #pragma unroll
        for (int i = 0; i < 4; i++) {
            int idx = t + i * 256;
            int kk = idx >> 6, c = idx & 63;
            Bs[kk][c] = Bm[(size_t)(k0 + kk) * N + c0 + c];
        }
        __syncthreads();
        #pragma unroll
        for (int kk = 0; kk < 16; kk++) {
            float a[4], b[4];
            #pragma unroll
            for (int i = 0; i < 4; i++) a[i] = As[ty * 4 + i][kk];
            #pragma unroll
            for (int j = 0; j < 4; j++) b[j] = Bs[kk][tx * 4 + j];
            #pragma unroll
            for (int i = 0; i < 4; i++)
                #pragma unroll
                for (int j = 0; j < 4; j++) acc[i][j] += a[i] * b[j];
        }
        __syncthreads();
    }

    #pragma unroll
    for (int i = 0; i < 4; i++) {
        int r = r0 + ty * 4 + i;
        #pragma unroll
        for (int j = 0; j < 4; j++) {
            int c = c0 + tx * 4 + j;
            float bv = bias ? bias[c] : 0.0f;
            C[(size_t)r * N + c] = acc[i][j] + bv;
        }
    }
}

// ---------------- QKV GEMM: fp32 compute, bf16 q/k/v outputs ----------------
// q,k: [b,h,n,64] token-major bf16.  v: [b,h,64,n] d-major bf16 (pre-transposed).
__global__ __launch_bounds__(256) void gemm_qkv(const float* __restrict__ A,
                                                const float* __restrict__ Bm,
                                                ushort_t* __restrict__ qb,
                                                ushort_t* __restrict__ kb,
                                                ushort_t* __restrict__ vb) {
    const int NN = 3 * D_;   // 1536
    __shared__ float As[64][17];
    __shared__ float Bs[16][65];
    const int c0 = blockIdx.x * 64;
    const int r0 = blockIdx.y * 64;
    const int t = threadIdx.x;
    const int tx = t & 15, ty = t >> 4;

    float acc[4][4] = {};

    for (int k0 = 0; k0 < D_; k0 += 16) {
        #pragma unroll
        for (int i = 0; i < 4; i++) {
            int idx = t + i * 256;
            int r = idx >> 4, kk = idx & 15;
            As[r][kk] = A[(size_t)(r0 + r) * D_ + k0 + kk];
        }
        #pragma unroll
        for (int i = 0; i < 4; i++) {
            int idx = t + i * 256;
            int kk = idx >> 6, c = idx & 63;
            Bs[kk][c] = Bm[(size_t)(k0 + kk) * NN + c0 + c];
        }
        __syncthreads();
        #pragma unroll
        for (int kk = 0; kk < 16; kk++) {
            float a[4], b[4];
            #pragma unroll
            for (int i = 0; i < 4; i++) a[i] = As[ty * 4 + i][kk];
            #pragma unroll
            for (int j = 0; j < 4; j++) b[j] = Bs[kk][tx * 4 + j];
            #pragma unroll
            for (int i = 0; i < 4; i++)
                #pragma unroll
                for (int j = 0; j < 4; j++) acc[i][j] += a[i] * b[j];
        }
        __syncthreads();
    }

    const int which = c0 >> 9;          // 0=q 1=k 2=v (uniform per block)
    const int h = (c0 >> 6) & 7;        // uniform per block
    if (which < 2) {
        ushort_t* dst = which == 0 ? qb : kb;
        #pragma unroll
        for (int i = 0; i < 4; i++) {
            int r = r0 + ty * 4 + i;
            int b = r >> 11, n = r & 2047;
            int d = tx * 4;
            union { ushort_t u4[4]; unsigned long long ll; } pk;
            #pragma unroll
            for (int j = 0; j < 4; j++) pk.u4[j] = f2bf(acc[i][j]);
            *(unsigned long long*)(dst + ((size_t)((b * H_ + h) * N_ + n)) * 64 + d) = pk.ll;
        }
    } else {
        #pragma unroll
        for (int j = 0; j < 4; j++) {
            int d = tx * 4 + j;
            int r = r0 + ty * 4;
            int b = r >> 11, n = r & 2047;
            union { ushort_t u4[4]; unsigned long long ll; } pk;
            #pragma unroll
            for (int i = 0; i < 4; i++) pk.u4[i] = f2bf(acc[i][j]);
            *(unsigned long long*)(vb + ((size_t)((b * H_ + h) * 64 + d)) * N_ + n) = pk.ll;
        }
    }
}

// ---------------- MFMA flash attention ----------------
// Block: 256 thr = 4 waves; wave w owns q rows n0+w*16..+15; key tiles of 64.
__global__ __launch_bounds__(256) void attn_mfma(const ushort_t* __restrict__ qb,
                                                 const ushort_t* __restrict__ kb,
                                                 const ushort_t* __restrict__ vb,
                                                 const float* __restrict__ rel,
                                                 const int* __restrict__ mask,
                                                 float* __restrict__ attn) {
    __shared__ float rel_s[2 * MAXREL + 1];
    __shared__ ushort_t p_s[2][4][16][72];   // [buf][wave][row][key(+pad)]

    const int t = threadIdx.x;
    const int w = t >> 6, lane = t & 63;
    const int m16 = lane & 15, quad = lane >> 4;
    const int qt = blockIdx.x, h = blockIdx.y, b = blockIdx.z;
    const int bh = b * H_ + h;
    const int n0 = qt * 64 + w * 16;

    for (int i = t; i < 2 * MAXREL + 1; i += 256) rel_s[i] = rel[i];

    const ushort_t* qp = qb + ((size_t)(bh * N_ + n0 + m16)) * 64 + quad * 8;
    bf16x8 qa0 = *(const bf16x8*)(qp);
    bf16x8 qa1 = *(const bf16x8*)(qp + 32);

    f32x4 o[4];
    #pragma unroll
    for (int nt = 0; nt < 4; nt++) o[nt] = (f32x4){0.f, 0.f, 0.f, 0.f};
    float m_r[4], l_r[4];
    #pragma unroll
    for (int r = 0; r < 4; r++) { m_r[r] = -1e30f; l_r[r] = 0.f; }
    int nrow[4];
    #pragma unroll
    for (int r = 0; r < 4; r++) nrow[r] = n0 + quad * 4 + r;

    const ushort_t* kp = kb + ((size_t)(bh * N_ + m16)) * 64 + quad * 8;
    const ushort_t* vp = vb + ((size_t)(bh * 64 + m16)) * N_ + quad * 8;

    __syncthreads();

    int buf = 0;
    for (int j0 = 0; j0 < N_; j0 += 64, buf ^= 1) {
        // ---- QK^T (K B-frags straight from global) ----
        f32x4 s[4];
        #pragma unroll
        for (int nt = 0; nt < 4; nt++) {
            const ushort_t* kr = kp + (size_t)(j0 + nt * 16) * 64;
            bf16x8 k0 = *(const bf16x8*)(kr);
            bf16x8 k1 = *(const bf16x8*)(kr + 32);
            f32x4 acc = (f32x4){0.f, 0.f, 0.f, 0.f};
            acc = __builtin_amdgcn_mfma_f32_16x16x32_bf16(qa0, k0, acc, 0, 0, 0);
            acc = __builtin_amdgcn_mfma_f32_16x16x32_bf16(qa1, k1, acc, 0, 0, 0);
            s[nt] = acc;
        }
        // ---- hoist V B-frags + mask loads ----
        bf16x8 vf[2][4];
        #pragma unroll
        for (int nt = 0; nt < 4; nt++) {
            const ushort_t* vr = vp + (size_t)(nt * 16) * N_ + j0;
            vf[0][nt] = *(const bf16x8*)(vr);
            vf[1][nt] = *(const bf16x8*)(vr + 32);
        }
        int mk[4][4];
        #pragma unroll
        for (int r = 0; r < 4; r++) {
            const int* mrow = mask + (size_t)nrow[r] * N_ + j0 + m16;
            #pragma unroll
            for (int nt = 0; nt < 4; nt++) mk[r][nt] = mrow[nt * 16];
        }
        // ---- bias + mask + online softmax (registers + shuffles only) ----
        float sv[4][4], mx[4];
        #pragma unroll
        for (int r = 0; r < 4; r++) mx[r] = -1e30f;
        #pragma unroll
        for (int nt = 0; nt < 4; nt++) {
            int mcol = j0 + nt * 16 + m16;
            #pragma unroll
            for (int r = 0; r < 4; r++) {
                float x = s[nt][r] * 0.125f;
                int dl = nrow[r] - mcol;
                dl = dl < -MAXREL ? -MAXREL : (dl > MAXREL ? MAXREL : dl);
                x += rel_s[dl + MAXREL];
                x = (mk[r][nt] == 0) ? -1e9f : x;
                sv[nt][r] = x;
                mx[r] = fmaxf(mx[r], x);
            }
        }
        float alpha[4], rs[4];
        #pragma unroll
        for (int r = 0; r < 4; r++) {
            float m2 = mx[r];
            m2 = fmaxf(m2, __shfl_xor(m2, 1));
            m2 = fmaxf(m2, __shfl_xor(m2, 2));
            m2 = fmaxf(m2, __shfl_xor(m2, 4));
            m2 = fmaxf(m2, __shfl_xor(m2, 8));
            float mn = fmaxf(m_r[r], m2);
            alpha[r] = __expf(m_r[r] - mn);
            m_r[r] = mn;
            rs[r] = 0.f;
        }
        ushort_t pv[4][4];
        #pragma unroll
        for (int nt = 0; nt < 4; nt++)
            #pragma unroll
            for (int r = 0; r < 4; r++) {
                float p = __expf(sv[nt][r] - m_r[r]);
                rs[r] += p;
                pv[nt][r] = f2bf(p);
            }
        #pragma unroll
        for (int r = 0; r < 4; r++) {
            float t2 = rs[r];
            t2 += __shfl_xor(t2, 1);
            t2 += __shfl_xor(t2, 2);
            t2 += __shfl_xor(t2, 4);
            t2 += __shfl_xor(t2, 8);
            l_r[r] = l_r[r] * alpha[r] + t2;
        }
        #pragma unroll
        for (int nt = 0; nt < 4; nt++)
            #pragma unroll
            for (int r = 0; r < 4; r++) o[nt][r] *= alpha[r];
        // ---- P: C-layout -> A-layout via per-wave LDS round trip ----
        #pragma unroll
        for (int r = 0; r < 4; r++)
            #pragma unroll
            for (int nt = 0; nt < 4; nt++)
                p_s[buf][w][quad * 4 + r][nt * 16 + m16] = pv[nt][r];
        __syncthreads();
        bf16x8 pa0 = *(const bf16x8*)(&p_s[buf][w][m16][quad * 8]);
        bf16x8 pa1 = *(const bf16x8*)(&p_s[buf][w][m16][32 + quad * 8]);
        // ---- P·V ----
        #pragma unroll
        for (int nt = 0; nt < 4; nt++) {
            o[nt] = __builtin_amdgcn_mfma_f32_16x16x32_bf16(pa0, vf[0][nt], o[nt], 0, 0, 0);
            o[nt] = __builtin_amdgcn_mfma_f32_16x16x32_bf16(pa1, vf[1][nt], o[nt], 0, 0, 0);
        }
    }

    #pragma unroll
    for (int r = 0; r < 4; r++) {
        float inv = 1.0f / l_r[r];
        float* orow = attn + ((size_t)(b * N_ + nrow[r])) * 512 + h * 64 + m16;
        #pragma unroll
        for (int nt = 0; nt < 4; nt++) orow[nt * 16] = o[nt][r] * inv;
    }
}

extern "C" void kernel_launch(void* const* d_in, const int* in_sizes, int n_in,
                              void* d_out, int out_size, void* d_ws, size_t ws_size,
                              hipStream_t stream) {
    const float* x     = (const float*)d_in[0];
    const float* gamma = (const float*)d_in[1];
    const float* beta  = (const float*)d_in[2];
    const float* Wqkv  = (const float*)d_in[3];
    const float* Wout  = (const float*)d_in[4];
    const float* bout  = (const float*)d_in[5];
    const float* rel   = (const float*)d_in[6];
    const int*   mask  = (const int*)d_in[7];
    float* out = (float*)d_out;

    char* wsb = (char*)d_ws;
    float*    xn   = (float*)(wsb);                       // 16 MB
    float*    attn = (float*)(wsb + (16u << 20));         // 16 MB
    ushort_t* qb   = (ushort_t*)(wsb + (32u << 20));      // 8 MB
    ushort_t* kb   = (ushort_t*)(wsb + (40u << 20));      // 8 MB
    ushort_t* vb   = (ushort_t*)(wsb + (48u << 20));      // 8 MB

    // 1. LayerNorm
    ln_kernel<<<B_ * N_, 256, 0, stream>>>(x, gamma, beta, xn);

    // 2. QKV projection -> bf16 q/k/v (v pre-transposed)
    gemm_qkv<<<dim3(1536 / 64, 8192 / 64), 256, 0, stream>>>(xn, Wqkv, qb, kb, vb);

    // 3. MFMA flash attention
    attn_mfma<<<dim3(N_ / 64, H_, B_), 256, 0, stream>>>(qb, kb, vb, rel, mask, attn);

    // 4. output projection + bias
    gemm_bias_kernel<<<dim3(512 / 64, 8192 / 64), 256, 0, stream>>>(
        attn, Wout, bout, out, B_ * N_, 512, D_);
}

// Round 3
// 386.049 us; speedup vs baseline: 5.5586x; 2.0689x over previous
//
#include <hip/hip_runtime.h>

typedef __attribute__((ext_vector_type(8))) short bf16x8;
typedef __attribute__((ext_vector_type(4))) float f32x4;
typedef unsigned short ushort_t;

#define B_ 4
#define H_ 8
#define N_ 2048
#define D_ 512
#define MAXREL 199   // MAX_REL-1

__device__ __forceinline__ ushort_t f2bf(float f) {
    union { float f; unsigned u; } v; v.f = f;
    unsigned r = v.u + 0x7fffu + ((v.u >> 16) & 1u);
    return (ushort_t)(r >> 16);
}

// ---------------- LayerNorm -> bf16 ----------------
__global__ __launch_bounds__(256) void ln_kernel(const float* __restrict__ x,
                                                 const float* __restrict__ gamma,
                                                 const float* __restrict__ beta,
                                                 ushort_t* __restrict__ xn) {
    __shared__ float sbuf[4];
    const int row = blockIdx.x;
    const int t = threadIdx.x;
    const float* xr = x + (size_t)row * D_;

    float v0 = xr[t];
    float v1 = xr[t + 256];

    float s = v0 + v1;
    for (int o = 32; o > 0; o >>= 1) s += __shfl_down(s, o);
    if ((t & 63) == 0) sbuf[t >> 6] = s;
    __syncthreads();
    float mu = (sbuf[0] + sbuf[1] + sbuf[2] + sbuf[3]) * (1.0f / D_);
    __syncthreads();

    float d0 = v0 - mu, d1 = v1 - mu;
    float s2 = d0 * d0 + d1 * d1;
    for (int o = 32; o > 0; o >>= 1) s2 += __shfl_down(s2, o);
    if ((t & 63) == 0) sbuf[t >> 6] = s2;
    __syncthreads();
    float var = (sbuf[0] + sbuf[1] + sbuf[2] + sbuf[3]) * (1.0f / D_);
    float rs = rsqrtf(var + 1e-5f);

    ushort_t* yr = xn + (size_t)row * D_;
    yr[t]       = f2bf(d0 * rs * gamma[t]       + beta[t]);
    yr[t + 256] = f2bf(d1 * rs * gamma[t + 256] + beta[t + 256]);
}

// ---------------- W [K][Nn] fp32 -> Wt [Nn][K] bf16 ----------------
__global__ __launch_bounds__(256) void wtrans_kernel(const float* __restrict__ W,
                                                     ushort_t* __restrict__ Wt,
                                                     int K, int Nn) {
    __shared__ float tile[32][33];
    const int bx = blockIdx.x * 32;   // n
    const int by = blockIdx.y * 32;   // k
    const int tx = threadIdx.x & 31, ty = threadIdx.x >> 5;
    #pragma unroll
    for (int i = 0; i < 32; i += 8)
        tile[ty + i][tx] = W[(size_t)(by + ty + i) * Nn + bx + tx];
    __syncthreads();
    #pragma unroll
    for (int i = 0; i < 32; i += 8)
        Wt[(size_t)(bx + ty + i) * K + by + tx] = f2bf(tile[tx][ty + i]);
}

// ---------------- bf16 MFMA GEMM core macro-parts ----------------
// A [M][512] bf16 row-major, Bt [Nn][512] bf16 row-major (pre-transposed).
// 128x128 tile, BK=32, 256 thr = 4 waves, wave = 64x64 (4x4 of 16x16).

// QKV: Nn=1536; epilogue scatters to q/k token-major, v d-major, all bf16.
__global__ __launch_bounds__(256) void gemm_qkv(const ushort_t* __restrict__ A,
                                                const ushort_t* __restrict__ Bt,
                                                ushort_t* __restrict__ qb,
                                                ushort_t* __restrict__ kb,
                                                ushort_t* __restrict__ vb) {
    __shared__ ushort_t As[128 * 32];
    __shared__ ushort_t Bs[128 * 32];
    const int t = threadIdx.x;
    const int lane = t & 63, w = t >> 6;
    const int m16 = lane & 15, quad = lane >> 4;
    const int wr = w >> 1, wc = w & 1;
    const int r0 = blockIdx.y * 128, c0 = blockIdx.x * 128;

    f32x4 acc[4][4];
    #pragma unroll
    for (int i = 0; i < 4; i++)
        #pragma unroll
        for (int j = 0; j < 4; j++) acc[i][j] = (f32x4){0.f, 0.f, 0.f, 0.f};

    for (int k0 = 0; k0 < D_; k0 += 32) {
        #pragma unroll
        for (int i = 0; i < 2; i++) {
            int f = t + i * 256;
            int row = f >> 2, kq = f & 3;
            *(bf16x8*)(As + f * 8) = *(const bf16x8*)(A + (size_t)(r0 + row) * D_ + k0 + kq * 8);
            *(bf16x8*)(Bs + f * 8) = *(const bf16x8*)(Bt + (size_t)(c0 + row) * D_ + k0 + kq * 8);
        }
        __syncthreads();
        bf16x8 af[4], bfr[4];
        #pragma unroll
        for (int rt = 0; rt < 4; rt++)
            af[rt] = *(const bf16x8*)(As + (wr * 64 + rt * 16 + m16) * 32 + quad * 8);
        #pragma unroll
        for (int ct = 0; ct < 4; ct++)
            bfr[ct] = *(const bf16x8*)(Bs + (wc * 64 + ct * 16 + m16) * 32 + quad * 8);
        #pragma unroll
        for (int rt = 0; rt < 4; rt++)
            #pragma unroll
            for (int ct = 0; ct < 4; ct++)
                acc[rt][ct] = __builtin_amdgcn_mfma_f32_16x16x32_bf16(af[rt], bfr[ct], acc[rt][ct], 0, 0, 0);
        __syncthreads();
    }

    #pragma unroll
    for (int ct = 0; ct < 4; ct++) {
        int cc = c0 + wc * 64 + ct * 16;      // 16-aligned, uniform per ct
        int which = cc >> 9;
        int h = (cc >> 6) & 7;
        int d = (cc & 63) + m16;
        #pragma unroll
        for (int rt = 0; rt < 4; rt++) {
            int rowb = r0 + wr * 64 + rt * 16 + quad * 4;
            int b = rowb >> 11, n0 = rowb & 2047;
            if (which < 2) {
                ushort_t* dst = which == 0 ? qb : kb;
                #pragma unroll
                for (int r = 0; r < 4; r++)
                    dst[((size_t)((b * H_ + h) * N_ + n0 + r)) * 64 + d] = f2bf(acc[rt][ct][r]);
            } else {
                union { ushort_t u4[4]; unsigned long long ll; } pk;
                #pragma unroll
                for (int r = 0; r < 4; r++) pk.u4[r] = f2bf(acc[rt][ct][r]);
                *(unsigned long long*)(vb + ((size_t)((b * H_ + h) * 64 + d)) * N_ + n0) = pk.ll;
            }
        }
    }
}

// Out-proj: Nn=512; C fp32 + bias.
__global__ __launch_bounds__(256) void gemm_out(const ushort_t* __restrict__ A,
                                                const ushort_t* __restrict__ Bt,
                                                const float* __restrict__ bias,
                                                float* __restrict__ C) {
    __shared__ ushort_t As[128 * 32];
    __shared__ ushort_t Bs[128 * 32];
    const int t = threadIdx.x;
    const int lane = t & 63, w = t >> 6;
    const int m16 = lane & 15, quad = lane >> 4;
    const int wr = w >> 1, wc = w & 1;
    const int r0 = blockIdx.y * 128, c0 = blockIdx.x * 128;

    f32x4 acc[4][4];
    #pragma unroll
    for (int i = 0; i < 4; i++)
        #pragma unroll
        for (int j = 0; j < 4; j++) acc[i][j] = (f32x4){0.f, 0.f, 0.f, 0.f};

    for (int k0 = 0; k0 < D_; k0 += 32) {
        #pragma unroll
        for (int i = 0; i < 2; i++) {
            int f = t + i * 256;
            int row = f >> 2, kq = f & 3;
            *(bf16x8*)(As + f * 8) = *(const bf16x8*)(A + (size_t)(r0 + row) * D_ + k0 + kq * 8);
            *(bf16x8*)(Bs + f * 8) = *(const bf16x8*)(Bt + (size_t)(c0 + row) * D_ + k0 + kq * 8);
        }
        __syncthreads();
        bf16x8 af[4], bfr[4];
        #pragma unroll
        for (int rt = 0; rt < 4; rt++)
            af[rt] = *(const bf16x8*)(As + (wr * 64 + rt * 16 + m16) * 32 + quad * 8);
        #pragma unroll
        for (int ct = 0; ct < 4; ct++)
            bfr[ct] = *(const bf16x8*)(Bs + (wc * 64 + ct * 16 + m16) * 32 + quad * 8);
        #pragma unroll
        for (int rt = 0; rt < 4; rt++)
            #pragma unroll
            for (int ct = 0; ct < 4; ct++)
                acc[rt][ct] = __builtin_amdgcn_mfma_f32_16x16x32_bf16(af[rt], bfr[ct], acc[rt][ct], 0, 0, 0);
        __syncthreads();
    }

    #pragma unroll
    for (int rt = 0; rt < 4; rt++) {
        #pragma unroll
        for (int ct = 0; ct < 4; ct++) {
            int col = c0 + wc * 64 + ct * 16 + m16;
            int row0 = r0 + wr * 64 + rt * 16 + quad * 4;
            float bv = bias[col];
            #pragma unroll
            for (int r = 0; r < 4; r++)
                C[(size_t)(row0 + r) * 512 + col] = acc[rt][ct][r] + bv;
        }
    }
}

// ---------------- MFMA flash attention (no per-tile barrier) ----------------
__global__ __launch_bounds__(256) void attn_mfma(const ushort_t* __restrict__ qb,
                                                 const ushort_t* __restrict__ kb,
                                                 const ushort_t* __restrict__ vb,
                                                 const float* __restrict__ rel,
                                                 const int* __restrict__ mask,
                                                 ushort_t* __restrict__ attn) {
    __shared__ float rel_s[2 * MAXREL + 1];
    __shared__ ushort_t p_s[2][4][16][72];   // [buf][wave][row][key(+pad)]

    const int t = threadIdx.x;
    const int w = t >> 6, lane = t & 63;
    const int m16 = lane & 15, quad = lane >> 4;
    const int qt = blockIdx.x, h = blockIdx.y, b = blockIdx.z;
    const int bh = b * H_ + h;
    const int n0 = qt * 64 + w * 16;

    for (int i = t; i < 2 * MAXREL + 1; i += 256) rel_s[i] = rel[i];

    const ushort_t* qp = qb + ((size_t)(bh * N_ + n0 + m16)) * 64 + quad * 8;
    bf16x8 qa0 = *(const bf16x8*)(qp);
    bf16x8 qa1 = *(const bf16x8*)(qp + 32);

    f32x4 o[4];
    #pragma unroll
    for (int nt = 0; nt < 4; nt++) o[nt] = (f32x4){0.f, 0.f, 0.f, 0.f};
    float m_r[4], l_r[4];
    #pragma unroll
    for (int r = 0; r < 4; r++) { m_r[r] = -1e30f; l_r[r] = 0.f; }
    int nrow[4];
    #pragma unroll
    for (int r = 0; r < 4; r++) nrow[r] = n0 + quad * 4 + r;

    const ushort_t* kp = kb + ((size_t)(bh * N_ + m16)) * 64 + quad * 8;
    const ushort_t* vp = vb + ((size_t)(bh * 64 + m16)) * N_ + quad * 8;

    __syncthreads();   // rel_s ready (only block-wide barrier)

    int buf = 0;
    for (int j0 = 0; j0 < N_; j0 += 64, buf ^= 1) {
        f32x4 s[4];
        #pragma unroll
        for (int nt = 0; nt < 4; nt++) {
            const ushort_t* kr = kp + (size_t)(j0 + nt * 16) * 64;
            bf16x8 k0 = *(const bf16x8*)(kr);
            bf16x8 k1 = *(const bf16x8*)(kr + 32);
            f32x4 acc2 = (f32x4){0.f, 0.f, 0.f, 0.f};
            acc2 = __builtin_amdgcn_mfma_f32_16x16x32_bf16(qa0, k0, acc2, 0, 0, 0);
            acc2 = __builtin_amdgcn_mfma_f32_16x16x32_bf16(qa1, k1, acc2, 0, 0, 0);
            s[nt] = acc2;
        }
        bf16x8 vf[2][4];
        #pragma unroll
        for (int nt = 0; nt < 4; nt++) {
            const ushort_t* vr = vp + (size_t)(nt * 16) * N_ + j0;
            vf[0][nt] = *(const bf16x8*)(vr);
            vf[1][nt] = *(const bf16x8*)(vr + 32);
        }
        int mk[4][4];
        #pragma unroll
        for (int r = 0; r < 4; r++) {
            const int* mrow = mask + (size_t)nrow[r] * N_ + j0 + m16;
            #pragma unroll
            for (int nt = 0; nt < 4; nt++) mk[r][nt] = mrow[nt * 16];
        }
        float sv[4][4], mx[4];
        #pragma unroll
        for (int r = 0; r < 4; r++) mx[r] = -1e30f;
        #pragma unroll
        for (int nt = 0; nt < 4; nt++) {
            int mcol = j0 + nt * 16 + m16;
            #pragma unroll
            for (int r = 0; r < 4; r++) {
                float x = s[nt][r] * 0.125f;
                int dl = nrow[r] - mcol;
                dl = dl < -MAXREL ? -MAXREL : (dl > MAXREL ? MAXREL : dl);
                x += rel_s[dl + MAXREL];
                x = (mk[r][nt] == 0) ? -1e9f : x;
                sv[nt][r] = x;
                mx[r] = fmaxf(mx[r], x);
            }
        }
        float alpha[4], rs[4];
        #pragma unroll
        for (int r = 0; r < 4; r++) {
            float m2 = mx[r];
            m2 = fmaxf(m2, __shfl_xor(m2, 1));
            m2 = fmaxf(m2, __shfl_xor(m2, 2));
            m2 = fmaxf(m2, __shfl_xor(m2, 4));
            m2 = fmaxf(m2, __shfl_xor(m2, 8));
            float mn = fmaxf(m_r[r], m2);
            alpha[r] = __expf(m_r[r] - mn);
            m_r[r] = mn;
            rs[r] = 0.f;
        }
        ushort_t pv[4][4];
        #pragma unroll
        for (int nt = 0; nt < 4; nt++)
            #pragma unroll
            for (int r = 0; r < 4; r++) {
                float p = __expf(sv[nt][r] - m_r[r]);
                rs[r] += p;
                pv[nt][r] = f2bf(p);
            }
        #pragma unroll
        for (int r = 0; r < 4; r++) {
            float t2 = rs[r];
            t2 += __shfl_xor(t2, 1);
            t2 += __shfl_xor(t2, 2);
            t2 += __shfl_xor(t2, 4);
            t2 += __shfl_xor(t2, 8);
            l_r[r] = l_r[r] * alpha[r] + t2;
        }
        #pragma unroll
        for (int nt = 0; nt < 4; nt++)
            #pragma unroll
            for (int r = 0; r < 4; r++) o[nt][r] *= alpha[r];
        // per-wave LDS round trip (no block barrier needed)
        #pragma unroll
        for (int r = 0; r < 4; r++)
            #pragma unroll
            for (int nt = 0; nt < 4; nt++)
                p_s[buf][w][quad * 4 + r][nt * 16 + m16] = pv[nt][r];
        bf16x8 pa0 = *(const bf16x8*)(&p_s[buf][w][m16][quad * 8]);
        bf16x8 pa1 = *(const bf16x8*)(&p_s[buf][w][m16][32 + quad * 8]);
        #pragma unroll
        for (int nt = 0; nt < 4; nt++) {
            o[nt] = __builtin_amdgcn_mfma_f32_16x16x32_bf16(pa0, vf[0][nt], o[nt], 0, 0, 0);
            o[nt] = __builtin_amdgcn_mfma_f32_16x16x32_bf16(pa1, vf[1][nt], o[nt], 0, 0, 0);
        }
    }

    #pragma unroll
    for (int r = 0; r < 4; r++) {
        float inv = 1.0f / l_r[r];
        ushort_t* orow = attn + ((size_t)(b * N_ + nrow[r])) * 512 + h * 64 + m16;
        #pragma unroll
        for (int nt = 0; nt < 4; nt++) orow[nt * 16] = f2bf(o[nt][r] * inv);
    }
}

extern "C" void kernel_launch(void* const* d_in, const int* in_sizes, int n_in,
                              void* d_out, int out_size, void* d_ws, size_t ws_size,
                              hipStream_t stream) {
    const float* x     = (const float*)d_in[0];
    const float* gamma = (const float*)d_in[1];
    const float* beta  = (const float*)d_in[2];
    const float* Wqkv  = (const float*)d_in[3];
    const float* Wout  = (const float*)d_in[4];
    const float* bout  = (const float*)d_in[5];
    const float* rel   = (const float*)d_in[6];
    const int*   mask  = (const int*)d_in[7];
    float* out = (float*)d_out;

    char* wsb = (char*)d_ws;
    ushort_t* xn    = (ushort_t*)(wsb);                    //  8 MB
    ushort_t* attnb = (ushort_t*)(wsb + ( 8u << 20));      //  8 MB
    ushort_t* qb    = (ushort_t*)(wsb + (16u << 20));      //  8 MB
    ushort_t* kb    = (ushort_t*)(wsb + (24u << 20));      //  8 MB
    ushort_t* vb    = (ushort_t*)(wsb + (32u << 20));      //  8 MB
    ushort_t* WqkvT = (ushort_t*)(wsb + (40u << 20));      //  1.5 MB
    ushort_t* WoutT = (ushort_t*)(wsb + (42u << 20));      //  0.5 MB

    // weight transposes (fp32 -> bf16 [N][K])
    wtrans_kernel<<<dim3(1536 / 32, 512 / 32), 256, 0, stream>>>(Wqkv, WqkvT, 512, 1536);
    wtrans_kernel<<<dim3(512 / 32, 512 / 32), 256, 0, stream>>>(Wout, WoutT, 512, 512);

    // 1. LayerNorm -> bf16
    ln_kernel<<<B_ * N_, 256, 0, stream>>>(x, gamma, beta, xn);

    // 2. QKV projection (MFMA) -> bf16 q/k/v (v pre-transposed)
    gemm_qkv<<<dim3(1536 / 128, 8192 / 128), 256, 0, stream>>>(xn, WqkvT, qb, kb, vb);

    // 3. MFMA flash attention -> bf16
    attn_mfma<<<dim3(N_ / 64, H_, B_), 256, 0, stream>>>(qb, kb, vb, rel, mask, attnb);

    // 4. output projection + bias (MFMA) -> fp32
    gemm_out<<<dim3(512 / 128, 8192 / 128), 256, 0, stream>>>(attnb, WoutT, bout, out);
}